// Round 1
// 367.366 us; speedup vs baseline: 1.0033x; 1.0033x over previous
//
#include <hip/hip_runtime.h>

#define NB 256              // histogram bins
#define NCH 48              // B*C = 16*3
#define HW (1024*1024)      // elements per channel
#define WPC (HW / 4)        // packed words per channel = 262144
#define BPC 32              // fused-path blocks per channel
#define GRID (NCH * BPC)    // 1536 -> needs 6 blocks/CU co-resident
#define THREADS 256
#define KTOT 32             // packed words per thread
#define KLDS 6              // first 6 words live in LDS (6 KB/block)
#define KREG (KTOT - KLDS)  // remaining 26 words live in registers
#define FB_BPC 64           // fallback blocks per channel
#define BAR_STRIDE 16       // uints -> 64 B per channel counter (own cacheline)

__device__ __forceinline__ int quant255(float v) {
    v = fminf(fmaxf(v, 0.0f), 1.0f);
    int q = (int)(v * 255.0f);     // fp32 mul + trunc, same as jnp
    q = q < 0 ? 0 : q;
    q = q > 255 ? 255 : q;
    return q;
}

__device__ __forceinline__ unsigned quant_pack(float4 v, unsigned* lh, int w) {
    int q0 = quant255(v.x), q1 = quant255(v.y);
    int q2 = quant255(v.z), q3 = quant255(v.w);
    atomicAdd(&lh[w * NB + q0], 1u);
    atomicAdd(&lh[w * NB + q1], 1u);
    atomicAdd(&lh[w * NB + q2], 1u);
    atomicAdd(&lh[w * NB + q3], 1u);
    return (unsigned)q0 | ((unsigned)q1 << 8)
         | ((unsigned)q2 << 16) | ((unsigned)q3 << 24);
}

// ---------------- Fused single-pass kernel (per-channel software barrier) --
// LDS: 6 KB packed q + 4 KB hist = 10240 B. VGPR capped at 85 by
// launch_bounds(256,6) -> 6 waves/EU. Host only launches this if the
// occupancy query confirms >= 6 blocks/CU, so all 1536 blocks are
// co-resident and every per-channel barrier is deadlock-free.
//
// R(prev) lesson candidate: the old GRID-wide barrier polled with
// atomicAdd(bar,0) -- a device-scope RMW on ONE cacheline from 1536 waves.
// Contended cross-XCD RMWs serialize (~100+ns each); releasing all waiters
// alone costs O(GRID * RMW-latency). Replaced with:
//   * 48 per-channel counters, 64 B apart (32 arrivals each, no global
//     straggler coupling)
//   * poll via agent-scope atomic LOAD (sc-bit L1/L2 bypass: coherent but
//     shareable -- pollers served in parallel, no exclusive ownership)
//   * ghist re-read via agent-scope load instead of atomicAdd(,0) RMW
__global__ __launch_bounds__(THREADS, 6) void fused_he_kernel(
    const float* __restrict__ x, unsigned int* __restrict__ ghist,
    unsigned int* __restrict__ bar, float* __restrict__ y) {
    __shared__ unsigned int sq[KLDS * THREADS];   // 6 KB packed q
    __shared__ unsigned int lh[4 * NB];           // 4 KB hist; reused for scan/LUT

    const int t  = threadIdx.x;
    const int w  = t >> 6;
    const int ch  = blockIdx.x / BPC;
    const int blk = blockIdx.x % BPC;

    for (int i = t; i < 4 * NB; i += THREADS) lh[i] = 0u;
    __syncthreads();

    const float4* xp = (const float4*)x + (size_t)ch * WPC
                       + (size_t)blk * (KTOT * THREADS);

    // Phase 1a: first KLDS words -> LDS (runtime loop, low reg pressure)
    for (int k = 0; k < KLDS; ++k) {
        float4 v = xp[k * THREADS + t];
        sq[k * THREADS + t] = quant_pack(v, lh, w);
    }
    // Phase 1b: remaining words -> registers (must fully unroll: const idx)
    unsigned int qpk[KREG];
    #pragma unroll
    for (int k = 0; k < KREG; ++k) {
        float4 v = xp[(KLDS + k) * THREADS + t];
        qpk[k] = quant_pack(v, lh, w);
    }
    __syncthreads();

    // Block hist -> global (one atomic per bin per block)
    unsigned int s = lh[t] + lh[NB + t] + lh[2 * NB + t] + lh[3 * NB + t];
    atomicAdd(&ghist[ch * NB + t], s);
    __threadfence();
    __syncthreads();

    // Per-channel software barrier: 32 arrivals on a dedicated cacheline.
    // Release-add on arrival; acquire-LOAD (not RMW) polling.
    unsigned int* barch = bar + (size_t)ch * BAR_STRIDE;
    if (t == 0) {
        __hip_atomic_fetch_add(barch, 1u, __ATOMIC_RELEASE,
                               __HIP_MEMORY_SCOPE_AGENT);
        while (__hip_atomic_load(barch, __ATOMIC_ACQUIRE,
                                 __HIP_MEMORY_SCOPE_AGENT) < (unsigned)BPC)
            __builtin_amdgcn_s_sleep(16);
    }
    __syncthreads();

    // Phase 2: CDF scan in LDS (aliased onto dead hist array).
    // Partials are integers < 2^24 -> exact fp32. Coherent ghist read via
    // agent-scope atomic load (bypasses stale L1/per-XCD L2, but is a
    // plain load at the LLC -- no serialized RMW).
    float* sbuf = (float*)lh;        // lh[0..255]
    float* lut  = (float*)lh + NB;   // lh[256..511]
    sbuf[t] = (float)__hip_atomic_load(&ghist[ch * NB + t], __ATOMIC_RELAXED,
                                       __HIP_MEMORY_SCOPE_AGENT);
    __syncthreads();
    for (int off = 1; off < NB; off <<= 1) {
        float add = (t >= off) ? sbuf[t - off] : 0.0f;
        __syncthreads();
        sbuf[t] += add;
        __syncthreads();
    }
    float total = sbuf[NB - 1];
    lut[t] = sbuf[t] / fmaxf(total, 1.0f);
    __syncthreads();

    // Phase 3: remap; lane-contiguous float4 stores
    float4* yp = (float4*)y + (size_t)ch * WPC + (size_t)blk * (KTOT * THREADS);
    for (int k = 0; k < KLDS; ++k) {
        unsigned p = sq[k * THREADS + t];
        yp[k * THREADS + t] = make_float4(lut[p & 255], lut[(p >> 8) & 255],
                                          lut[(p >> 16) & 255], lut[p >> 24]);
    }
    #pragma unroll
    for (int k = 0; k < KREG; ++k) {
        unsigned p = qpk[k];
        yp[(KLDS + k) * THREADS + t] = make_float4(lut[p & 255], lut[(p >> 8) & 255],
                                                   lut[(p >> 16) & 255], lut[p >> 24]);
    }
}

// ---------------- Fallback path (proven R2 structure) ----------------
__global__ __launch_bounds__(THREADS) void hist_quant_kernel(
    const float* __restrict__ x, unsigned int* __restrict__ ghist,
    unsigned int* __restrict__ q) {
    __shared__ unsigned int lh[4 * NB];
    const int t = threadIdx.x;
    const int w = t >> 6;
    for (int i = t; i < 4 * NB; i += THREADS) lh[i] = 0u;
    __syncthreads();

    const int ch  = blockIdx.x / FB_BPC;
    const int blk = blockIdx.x % FB_BPC;
    const float4* xp = (const float4*)(x + (size_t)ch * HW);
    unsigned int* qp = q + (size_t)ch * WPC;
    const int n4 = WPC / FB_BPC;
    const int base = blk * n4;

    for (int i = base + t; i < base + n4; i += THREADS) {
        float4 v = xp[i];
        qp[i] = quant_pack(v, lh, w);
    }
    __syncthreads();
    unsigned int s = lh[t] + lh[NB + t] + lh[2 * NB + t] + lh[3 * NB + t];
    if (s) atomicAdd(&ghist[ch * NB + t], s);
}

__global__ __launch_bounds__(THREADS) void cdf_remap_kernel(
    const unsigned int* __restrict__ q, const unsigned int* __restrict__ ghist,
    float* __restrict__ y) {
    __shared__ float sbuf[NB];
    __shared__ float lut[NB];
    const int t = threadIdx.x;
    const int ch  = blockIdx.x / FB_BPC;
    const int blk = blockIdx.x % FB_BPC;

    sbuf[t] = (float)ghist[ch * NB + t];
    __syncthreads();
    for (int off = 1; off < NB; off <<= 1) {
        float add = (t >= off) ? sbuf[t - off] : 0.0f;
        __syncthreads();
        sbuf[t] += add;
        __syncthreads();
    }
    float total = sbuf[NB - 1];
    lut[t] = sbuf[t] / fmaxf(total, 1.0f);
    __syncthreads();

    // lane-contiguous: 4 B packed read + 16 B float4 write per thread
    const unsigned int* qp = q + (size_t)ch * WPC;
    float4*             yp = (float4*)(y + (size_t)ch * HW);
    const int n4 = WPC / FB_BPC;
    const int base = blk * n4;
    for (int i = base + t; i < base + n4; i += THREADS) {
        unsigned p = qp[i];
        yp[i] = make_float4(lut[p & 255], lut[(p >> 8) & 255],
                            lut[(p >> 16) & 255], lut[p >> 24]);
    }
}

extern "C" void kernel_launch(void* const* d_in, const int* in_sizes, int n_in,
                              void* d_out, int out_size, void* d_ws, size_t ws_size,
                              hipStream_t stream) {
    const float* x = (const float*)d_in[0];
    float* y = (float*)d_out;

    unsigned int* ghist = (unsigned int*)d_ws;                           // 48 KB
    unsigned int* bar   = (unsigned int*)((char*)d_ws + 60 * 1024);      // 48 x 64 B
    unsigned int* q     = (unsigned int*)((char*)d_ws + 256 * 1024);     // 48 MB (fallback)

    // zero ghist + per-channel barrier counters (ws is 0xAA-poisoned
    // before every launch)
    hipMemsetAsync(d_ws, 0, 64 * 1024, stream);

    // Host-side occupancy gate (capture-safe: pure query, no stream ops).
    // Fused path requires all 1536 blocks co-resident: >= 6 blocks/CU.
    int occ = 0;
    hipError_t qe = hipOccupancyMaxActiveBlocksPerMultiprocessor(
        &occ, fused_he_kernel, THREADS, 0);
    bool fused_ok = (qe == hipSuccess) && (occ >= GRID / 256);

    if (fused_ok) {
        fused_he_kernel<<<GRID, THREADS, 0, stream>>>(x, ghist, bar, y);
    } else {
        hist_quant_kernel<<<NCH * FB_BPC, THREADS, 0, stream>>>(x, ghist, q);
        cdf_remap_kernel <<<NCH * FB_BPC, THREADS, 0, stream>>>(q, ghist, y);
    }
}

// Round 2
// 362.029 us; speedup vs baseline: 1.0181x; 1.0147x over previous
//
#include <hip/hip_runtime.h>

#define NB 256              // histogram bins
#define NCH 48              // B*C = 16*3
#define HW (1024*1024)      // elements per channel
#define WPC (HW / 4)        // packed words per channel = 262144
#define BPC 32              // fused-path blocks per channel
#define GRID (NCH * BPC)    // 1536 -> needs 6 blocks/CU co-resident
#define THREADS 256
#define KTOT 32             // packed words per thread
#define KLDS 6              // first 6 words live in LDS (6 KB/block)
#define KREG (KTOT - KLDS)  // remaining 26 words live in registers
#define FB_BPC 64           // fallback blocks per channel
#define BAR_STRIDE 16       // uints -> 64 B per channel counter (own cacheline)

__device__ __forceinline__ int quant255(float v) {
    v = fminf(fmaxf(v, 0.0f), 1.0f);
    int q = (int)(v * 255.0f);     // fp32 mul + trunc, same as jnp
    q = q < 0 ? 0 : q;
    q = q > 255 ? 255 : q;
    return q;
}

__device__ __forceinline__ unsigned quant_pack(float4 v, unsigned* lh, int w) {
    int q0 = quant255(v.x), q1 = quant255(v.y);
    int q2 = quant255(v.z), q3 = quant255(v.w);
    atomicAdd(&lh[w * NB + q0], 1u);
    atomicAdd(&lh[w * NB + q1], 1u);
    atomicAdd(&lh[w * NB + q2], 1u);
    atomicAdd(&lh[w * NB + q3], 1u);
    return (unsigned)q0 | ((unsigned)q1 << 8)
         | ((unsigned)q2 << 16) | ((unsigned)q3 << 24);
}

// ---------------- Fused single-pass kernel (per-channel software barrier) --
// LDS: 6 KB packed q + 4 KB hist = 10240 B. VGPR capped at 85 by
// launch_bounds(256,6) -> 6 waves/EU. Host only launches this if the
// occupancy query confirms >= 6 blocks/CU, so all 1536 blocks are
// co-resident and every per-channel barrier is deadlock-free.
//
// R2 theory: the old code ran __threadfence() in EVERY wave (6144 waves).
// On gfx950 an agent acq_rel fence must lower to s_waitcnt + buffer_wbl2 +
// buffer_inv because per-XCD L2s are non-coherent -- 6144 L2-wide
// writeback/invalidate ops serializing at 8 L2s, and each inv nukes live
// x/y lines (explains 1 TB/s streaming + 2.4% VALUBusy). The fence is
// unnecessary: ghist/bar communication uses agent-scope atomics which
// execute at the LLC (coherence point, L1/L2-bypassing), and the
// s_waitcnt vmcnt(0) inside __syncthreads() already drains each wave's
// no-return atomics before the barrier arrival. So: NO threadfence, and
// RELAXED (not acquire) polling so no per-poll cache invalidates.
__global__ __launch_bounds__(THREADS, 6) void fused_he_kernel(
    const float* __restrict__ x, unsigned int* __restrict__ ghist,
    unsigned int* __restrict__ bar, float* __restrict__ y) {
    __shared__ unsigned int sq[KLDS * THREADS];   // 6 KB packed q
    __shared__ unsigned int lh[4 * NB];           // 4 KB hist; reused for scan/LUT

    const int t  = threadIdx.x;
    const int w  = t >> 6;
    const int ch  = blockIdx.x / BPC;
    const int blk = blockIdx.x % BPC;

    for (int i = t; i < 4 * NB; i += THREADS) lh[i] = 0u;
    __syncthreads();

    const float4* xp = (const float4*)x + (size_t)ch * WPC
                       + (size_t)blk * (KTOT * THREADS);

    // Phase 1a: first KLDS words -> LDS (runtime loop, low reg pressure)
    for (int k = 0; k < KLDS; ++k) {
        float4 v = xp[k * THREADS + t];
        sq[k * THREADS + t] = quant_pack(v, lh, w);
    }
    // Phase 1b: remaining words -> registers (must fully unroll: const idx)
    unsigned int qpk[KREG];
    #pragma unroll
    for (int k = 0; k < KREG; ++k) {
        float4 v = xp[(KLDS + k) * THREADS + t];
        qpk[k] = quant_pack(v, lh, w);
    }
    __syncthreads();

    // Block hist -> global (one atomic per bin per block). Device-scope
    // atomicAdd executes at the LLC -- once vmcnt retires it is visible to
    // every XCD. No cache fence needed.
    unsigned int s = lh[t] + lh[NB + t] + lh[2 * NB + t] + lh[3 * NB + t];
    atomicAdd(&ghist[ch * NB + t], s);

    // __syncthreads emits s_waitcnt vmcnt(0) lgkmcnt(0) per wave before
    // s_barrier: all 4 waves' ghist atomics have completed at the LLC
    // before any thread proceeds. This replaces __threadfence().
    __syncthreads();

    // Per-channel software barrier: 32 arrivals on a dedicated cacheline.
    // RELAXED agent-scope ops: they execute at the LLC (coherent), and we
    // deliberately avoid acquire/release so the compiler emits NO
    // buffer_wbl2/buffer_inv cache-maintenance (nothing relevant is dirty
    // in L2 -- ghist ops are LLC atomics, sq/lh are LDS).
    unsigned int* barch = bar + (size_t)ch * BAR_STRIDE;
    if (t == 0) {
        __hip_atomic_fetch_add(barch, 1u, __ATOMIC_RELAXED,
                               __HIP_MEMORY_SCOPE_AGENT);
        while (__hip_atomic_load(barch, __ATOMIC_RELAXED,
                                 __HIP_MEMORY_SCOPE_AGENT) < (unsigned)BPC)
            __builtin_amdgcn_s_sleep(16);
    }
    __syncthreads();   // compiler + hardware ordering for the ghist reads below

    // Phase 2: CDF scan in LDS (aliased onto dead hist array).
    // Partials are integers < 2^24 -> exact fp32. Coherent ghist read via
    // relaxed agent-scope atomic load (L1/L2-bypassing LLC load -- no RMW,
    // no cache-maintenance).
    float* sbuf = (float*)lh;        // lh[0..255]
    float* lut  = (float*)lh + NB;   // lh[256..511]
    sbuf[t] = (float)__hip_atomic_load(&ghist[ch * NB + t], __ATOMIC_RELAXED,
                                       __HIP_MEMORY_SCOPE_AGENT);
    __syncthreads();
    for (int off = 1; off < NB; off <<= 1) {
        float add = (t >= off) ? sbuf[t - off] : 0.0f;
        __syncthreads();
        sbuf[t] += add;
        __syncthreads();
    }
    float total = sbuf[NB - 1];
    lut[t] = sbuf[t] / fmaxf(total, 1.0f);
    __syncthreads();

    // Phase 3: remap; lane-contiguous float4 stores
    float4* yp = (float4*)y + (size_t)ch * WPC + (size_t)blk * (KTOT * THREADS);
    for (int k = 0; k < KLDS; ++k) {
        unsigned p = sq[k * THREADS + t];
        yp[k * THREADS + t] = make_float4(lut[p & 255], lut[(p >> 8) & 255],
                                          lut[(p >> 16) & 255], lut[p >> 24]);
    }
    #pragma unroll
    for (int k = 0; k < KREG; ++k) {
        unsigned p = qpk[k];
        yp[(KLDS + k) * THREADS + t] = make_float4(lut[p & 255], lut[(p >> 8) & 255],
                                                   lut[(p >> 16) & 255], lut[p >> 24]);
    }
}

// ---------------- Fallback path (proven R2 structure) ----------------
__global__ __launch_bounds__(THREADS) void hist_quant_kernel(
    const float* __restrict__ x, unsigned int* __restrict__ ghist,
    unsigned int* __restrict__ q) {
    __shared__ unsigned int lh[4 * NB];
    const int t = threadIdx.x;
    const int w = t >> 6;
    for (int i = t; i < 4 * NB; i += THREADS) lh[i] = 0u;
    __syncthreads();

    const int ch  = blockIdx.x / FB_BPC;
    const int blk = blockIdx.x % FB_BPC;
    const float4* xp = (const float4*)(x + (size_t)ch * HW);
    unsigned int* qp = q + (size_t)ch * WPC;
    const int n4 = WPC / FB_BPC;
    const int base = blk * n4;

    for (int i = base + t; i < base + n4; i += THREADS) {
        float4 v = xp[i];
        qp[i] = quant_pack(v, lh, w);
    }
    __syncthreads();
    unsigned int s = lh[t] + lh[NB + t] + lh[2 * NB + t] + lh[3 * NB + t];
    if (s) atomicAdd(&ghist[ch * NB + t], s);
}

__global__ __launch_bounds__(THREADS) void cdf_remap_kernel(
    const unsigned int* __restrict__ q, const unsigned int* __restrict__ ghist,
    float* __restrict__ y) {
    __shared__ float sbuf[NB];
    __shared__ float lut[NB];
    const int t = threadIdx.x;
    const int ch  = blockIdx.x / FB_BPC;
    const int blk = blockIdx.x % FB_BPC;

    sbuf[t] = (float)ghist[ch * NB + t];
    __syncthreads();
    for (int off = 1; off < NB; off <<= 1) {
        float add = (t >= off) ? sbuf[t - off] : 0.0f;
        __syncthreads();
        sbuf[t] += add;
        __syncthreads();
    }
    float total = sbuf[NB - 1];
    lut[t] = sbuf[t] / fmaxf(total, 1.0f);
    __syncthreads();

    // lane-contiguous: 4 B packed read + 16 B float4 write per thread
    const unsigned int* qp = q + (size_t)ch * WPC;
    float4*             yp = (float4*)(y + (size_t)ch * HW);
    const int n4 = WPC / FB_BPC;
    const int base = blk * n4;
    for (int i = base + t; i < base + n4; i += THREADS) {
        unsigned p = qp[i];
        yp[i] = make_float4(lut[p & 255], lut[(p >> 8) & 255],
                            lut[(p >> 16) & 255], lut[p >> 24]);
    }
}

extern "C" void kernel_launch(void* const* d_in, const int* in_sizes, int n_in,
                              void* d_out, int out_size, void* d_ws, size_t ws_size,
                              hipStream_t stream) {
    const float* x = (const float*)d_in[0];
    float* y = (float*)d_out;

    unsigned int* ghist = (unsigned int*)d_ws;                           // 48 KB
    unsigned int* bar   = (unsigned int*)((char*)d_ws + 60 * 1024);      // 48 x 64 B
    unsigned int* q     = (unsigned int*)((char*)d_ws + 256 * 1024);     // 48 MB (fallback)

    // zero ghist + per-channel barrier counters (ws is 0xAA-poisoned
    // before every launch)
    hipMemsetAsync(d_ws, 0, 64 * 1024, stream);

    // Host-side occupancy gate (capture-safe: pure query, no stream ops).
    // Fused path requires all 1536 blocks co-resident: >= 6 blocks/CU.
    int occ = 0;
    hipError_t qe = hipOccupancyMaxActiveBlocksPerMultiprocessor(
        &occ, fused_he_kernel, THREADS, 0);
    bool fused_ok = (qe == hipSuccess) && (occ >= GRID / 256);

    if (fused_ok) {
        fused_he_kernel<<<GRID, THREADS, 0, stream>>>(x, ghist, bar, y);
    } else {
        hist_quant_kernel<<<NCH * FB_BPC, THREADS, 0, stream>>>(x, ghist, q);
        cdf_remap_kernel <<<NCH * FB_BPC, THREADS, 0, stream>>>(q, ghist, y);
    }
}